// Round 7
// baseline (179.654 us; speedup 1.0000x reference)
//
#include <hip/hip_runtime.h>

// Problem constants (RefinementLayer1): B=2, L=192, D=768, NC=4, H=256
#define LSEQ 192
#define DIM  768
#define NCASE 4
#define HID  256
#define BATCH 2

// tanh(x) = 1 - 2/(exp2(K*x)+1), K = 2*log2(e). K folded into Bpack so the
// refine epilogue's tanh input (acc = K*mid) needs no extra scale.
#define TANH_K 2.885390081777927f

typedef float  floatx4 __attribute__((ext_vector_type(4)));
typedef float  floatx2 __attribute__((ext_vector_type(2)));
typedef __bf16 bf16x8  __attribute__((ext_vector_type(8)));
typedef __bf16 bf16x4  __attribute__((ext_vector_type(4)));

__device__ __forceinline__ float tanh_pre(float x) {   // x already * TANH_K
    float e = __builtin_amdgcn_exp2f(x);
    return 1.0f - 2.0f * __builtin_amdgcn_rcpf(e + 1.0f);
}

// ---- packed fp32 pairs: NATIVE vector ops (backend selects v_pk_*_f32 with
// correct op_sel_hi; validated in R14-R18 passes).
__device__ __forceinline__ floatx2 pk_fma2(floatx2 a, floatx2 b, floatx2 c) {
    return __builtin_elementwise_fma(a, b, c);
}
__device__ __forceinline__ floatx2 pk_add2(floatx2 a, floatx2 b) { return a + b; }
__device__ __forceinline__ floatx2 pk_mul2(floatx2 a, floatx2 b) { return a * b; }

// tanh(u+v) = (tu+tv)/(1+tu*tv) from tu=tanh(u), tv=tanh(v).
// 8 elements: 4 pk_fma + 4 pk_add + 8 rcp + 4 pk_mul (validated R14/R15).
__device__ __forceinline__ bf16x8 tanh_add8(floatx4 u0, floatx4 u1,
                                            floatx4 v0, floatx4 v1) {
    const floatx2 one = {1.0f, 1.0f};
    float uu[8] = {u0[0], u0[1], u0[2], u0[3], u1[0], u1[1], u1[2], u1[3]};
    float vv[8] = {v0[0], v0[1], v0[2], v0[3], v1[0], v1[1], v1[2], v1[3]};
    bf16x8 r;
    #pragma unroll
    for (int i = 0; i < 4; i++) {
        floatx2 tu = {uu[2 * i], uu[2 * i + 1]};
        floatx2 tv = {vv[2 * i], vv[2 * i + 1]};
        floatx2 den = pk_fma2(tu, tv, one);
        floatx2 num = pk_add2(tu, tv);
        floatx2 rc;
        rc[0] = __builtin_amdgcn_rcpf(den[0]);
        rc[1] = __builtin_amdgcn_rcpf(den[1]);
        floatx2 res = pk_mul2(num, rc);
        r[2 * i]     = (__bf16)res[0];
        r[2 * i + 1] = (__bf16)res[1];
    }
    return r;
}

// Workgroup barrier draining ONLY lgkmcnt (LDS); global prefetches stay in
// flight. 0xC07F = vmcnt(63) expcnt(7) lgkmcnt(0).
__device__ __forceinline__ void barrier_lds_only() {
    __builtin_amdgcn_sched_barrier(0);
    __builtin_amdgcn_s_waitcnt(0xC07F);
    __builtin_amdgcn_s_barrier();
    __builtin_amdgcn_sched_barrier(0);
}

template <int CTRL>
__device__ __forceinline__ float dpp_add(float v) {
    int x = __builtin_amdgcn_update_dpp(0, __builtin_bit_cast(int, v),
                                        CTRL, 0xF, 0xF, true);
    return v + __builtin_bit_cast(float, x);
}
__device__ __forceinline__ float row16_reduce(float v) {
    v = dpp_add<0xB1>(v);    // quad_perm xor1
    v = dpp_add<0x4E>(v);    // quad_perm xor2
    v = dpp_add<0x141>(v);   // row_half_mirror
    v = dpp_add<0x140>(v);   // row_mirror
    return v;
}

// ---------------------------------------------------------------------------
// MFMA fragment layouts (m89/m91-verified, 16x16x32 bf16):
//   A: lane holds A[m = lane&15][k = (lane>>4)*8 + j]   (bf16x8)
//   B: lane holds B[k = (lane>>4)*8 + j][h = lane&15]   (bf16x8)
//   C/D: lane reg holds D[row = (lane>>4)*4 + reg][col = lane&15]
// ---------------------------------------------------------------------------

// ---------------------------------------------------------------------------
// Kernel 1 "prep" (unchanged — proven not the bottleneck).
// ---------------------------------------------------------------------------
__global__ __launch_bounds__(256) void prep(
    const float* __restrict__ seq, const float* __restrict__ Wp,
    const float* __restrict__ Wa,  const float* __restrict__ bp,
    const float* __restrict__ ba,  const float* __restrict__ Wmid,
    const float* __restrict__ bmid,
    float* __restrict__ lin, bf16x8* __restrict__ Bpack)
{
    const int blk = blockIdx.x;
    const int tid = threadIdx.x;

    if (blk >= 1920) {                     // ---- pack job
        int u = (blk - 1920) * 256 + tid;  // 0..36863 (one bf16x8 each)
        int lane = u & 63, f = u >> 6;
        int ct = f & 15, nk = f >> 4;      // nk = n*9 + kc
        int kc = nk % 9, n = nk / 9;
        int h = ct * 16 + (lane & 15);
        int kbase = kc * 32 + ((lane >> 4) & 3) * 8;
        bf16x8 v;
        #pragma unroll
        for (int j = 0; j < 8; j++) {
            int k = kbase + j;
            float x;
            if (k < 260)       x = Wmid[(size_t)(n * 260 + k) * 256 + h];
            else if (k == 260) x = bmid[n * 256 + h];
            else               x = 0.0f;
            v[j] = (__bf16)(TANH_K * x);
        }
        Bpack[u] = v;
        return;
    }

    // ---- lin unit: rt = blk/80, cg = blk%80; wave w = K-quarter
    const int w = tid >> 6, lane = tid & 63;
    const int rt = blk / 80, cg = blk % 80;
    const int quad  = lane >> 4;
    const int col16 = lane & 15;

    __shared__ float cmb[3][256];          // waves 1..3 partials, 3 KB

    const int arow = rt * 16 + col16;          // A: m = lane&15
    const int col  = cg * 16 + col16;          // output col 0..1279
    const int kofs = w * 192;
    const float* aptr = seq + (size_t)arow * DIM + kofs + quad * 8;
    const float* wbase = (cg < 16) ? (Wp + col) : (Wa + (col - 256));
    const int    wstr  = (cg < 16) ? HID : (NCASE * HID);

    floatx4 acc = {};
    floatx4 a0 = *(const floatx4*)(aptr);
    floatx4 a1 = *(const floatx4*)(aptr + 4);
    float bv[8];
    #pragma unroll
    for (int j = 0; j < 8; j++)
        bv[j] = wbase[(size_t)(kofs + quad * 8 + j) * wstr];

    #pragma unroll
    for (int kc = 0; kc < 6; kc++) {
        bf16x8 ah, al, bh, bl;
        #pragma unroll
        for (int j = 0; j < 4; j++) {
            __bf16 h0 = (__bf16)a0[j];
            ah[j] = h0; al[j] = (__bf16)(a0[j] - (float)h0);
            __bf16 h1 = (__bf16)a1[j];
            ah[4 + j] = h1; al[4 + j] = (__bf16)(a1[j] - (float)h1);
        }
        #pragma unroll
        for (int j = 0; j < 8; j++) {
            __bf16 h = (__bf16)bv[j];
            bh[j] = h; bl[j] = (__bf16)(bv[j] - (float)h);
        }
        if (kc < 5) {                      // prefetch next chunk
            a0 = *(const floatx4*)(aptr + (kc + 1) * 32);
            a1 = *(const floatx4*)(aptr + (kc + 1) * 32 + 4);
            #pragma unroll
            for (int j = 0; j < 8; j++)
                bv[j] = wbase[(size_t)(kofs + (kc + 1) * 32 + quad * 8 + j) * wstr];
        }
        acc = __builtin_amdgcn_mfma_f32_16x16x32_bf16(ah, bh, acc, 0, 0, 0);
        acc = __builtin_amdgcn_mfma_f32_16x16x32_bf16(al, bh, acc, 0, 0, 0);
        acc = __builtin_amdgcn_mfma_f32_16x16x32_bf16(ah, bl, acc, 0, 0, 0);
    }

    if (w > 0) *(floatx4*)&cmb[w - 1][lane * 4] = acc;
    __syncthreads();
    if (w == 0) {
        #pragma unroll
        for (int i = 0; i < 3; i++) {
            floatx4 p = *(const floatx4*)&cmb[i][lane * 4];
            acc += p;
        }
        const float bias = (cg < 16) ? bp[col] : ba[col - 256];
        #pragma unroll
        for (int reg = 0; reg < 4; reg++)
            lin[(size_t)(rt * 16 + quad * 4 + reg) * 1280 + col] =
                tanh_pre(TANH_K * (acc[reg] + bias));     // pre-activated
    }
}

// ---------------------------------------------------------------------------
// Kernel 2: fused main — R19: halve per-output LDS traffic.
// Diagnosis: the phase cost is dominated by the LDS pipe — 8 waves each
// re-read the same 4KB A-tile (4x ds_read_b128 @ ~12cyc) for only 2
// h-columns each (~30us LDS busy per CU, vs VALU 34us busy, MFMA 18us).
// All R13-R18 schedule variants kept this traffic constant -> 72-85us.
// Fix: 2 ptiles per block (128 rows = two 64-row A-tiles). Waves 0-3 consume
// tile 0, waves 4-7 tile 1; each wave owns 4 h-column-tiles (ct = wq*4+cc).
// Same af reads per wave per phase -> 2x MFMA output per read. Gen: each
// thread produces ONE full bf16x8 slot (tanh_add8) per phase — same total
// tanh work, single ds_write_b128. Loop skeleton = proven R16 (post-barrier
// af reads, gen 1 chunk ahead, parity ping-pong, lds-only barriers);
// B-frags = R18's validated reload-into-same-regs (bcur[4] = 16 VGPR).
// Grid: dim3(12*24, NC, B) = 2304 blocks.
// ---------------------------------------------------------------------------
__global__ __launch_bounds__(512, 4) void refine_main(
    const float* __restrict__ lin,        // [384][1280], PRE-TANH'd
    const float* __restrict__ base_score, // [B][L][NC][L]
    const float* __restrict__ Wout,       // [NC][256]
    const bf16x8* __restrict__ Bpack,     // packed Wmid frags (K-scaled)
    float* __restrict__ out)              // [B][L][NC][L]
{
    const int bx = blockIdx.x;            // 288 = 12*24
    const int n  = blockIdx.y;
    const int b  = blockIdx.z;
    const int p0  = (bx / 24) * 16;       // 16 p-rows (2 ptiles)
    const int a0r = (bx % 24) * 8;

    const int tid   = threadIdx.x;
    const int w     = tid >> 6;           // wave 0..7
    const int lane  = tid & 63;
    const int quad  = lane >> 4;
    const int col16 = lane & 15;
    const int T_r   = w >> 2;             // A-tile this wave consumes (0/1)
    const int wq    = w & 3;              // ct group: ct = wq*4 + cc

    // BUF[tile][parity][2048 bf16]: chunk kc of tile T lives in BUF[T][kc&1].
    __shared__ __align__(16) __bf16 BUF[2][2][2048];   // 16 KB
    __shared__ float red[8][64];                       //  2 KB

    // ---- gen slot: thread gens slot u of tile Tg (one bf16x8 per phase)
    const int Tg = tid >> 8;              // waves 0-3 gen tile 0, 4-7 tile 1
    const int u  = tid & 255;
    const int mg = ((u >> 6) << 4) + (u & 15);   // row in tile (matches af)
    const int k0 = ((u >> 4) & 3) * 8;           // k-offset in chunk
    const int pg = p0 + Tg * 8 + (mg >> 3);
    const int ag = a0r + (mg & 7);
    const float* hp_ptr = lin + (size_t)(b * LSEQ + pg) * 1280 + k0;
    const float* ha_ptr = lin + (size_t)(b * LSEQ + ag) * 1280 + 256 + n * 256 + k0;
    __bf16* wbase = &BUF[Tg][0][u * 8];

    // B frags for wave w: index ((n*9 + kc)*16 + wq*4 + cc)*64 + lane
    const bf16x8* bb = Bpack + ((size_t)(n * 9) * 16 + wq * 4) * 64 + lane;

    // ---- prologue
    float bs4[4] = {};
    if (k0 == 0) {
        #pragma unroll
        for (int j = 0; j < 4; j++)
            bs4[j] = base_score[((size_t)(b * LSEQ + pg) * NCASE + j) * LSEQ + ag];
    }

    bf16x8 bcur[4];
    #pragma unroll
    for (int cc = 0; cc < 4; cc++) bcur[cc] = bb[cc * 64];   // chunk 0

    floatx4 u0 = *(const floatx4*)(hp_ptr);
    floatx4 u1 = *(const floatx4*)(hp_ptr + 4);
    floatx4 v0 = *(const floatx4*)(ha_ptr);
    floatx4 v1 = *(const floatx4*)(ha_ptr + 4);
    *(bf16x8*)wbase = tanh_add8(u0, u1, v0, v1);     // av(0) -> parity 0
    u0 = *(const floatx4*)(hp_ptr + 32);             // chunk 1 inputs
    u1 = *(const floatx4*)(hp_ptr + 36);
    v0 = *(const floatx4*)(ha_ptr + 32);
    v1 = *(const floatx4*)(ha_ptr + 36);
    barrier_lds_only();

    floatx4 acc[4][4] = {};   // [rt][cc]

    #pragma unroll
    for (int kc = 0; kc < 9; kc++) {
        // af(kc) from BUF[T_r][kc&1] (post-barrier ds_read, R16-proven)
        const __bf16* rb = &BUF[T_r][kc & 1][0];
        bf16x8 af[4];
        #pragma unroll
        for (int rt = 0; rt < 4; rt++)
            af[rt] = *(const bf16x8*)&rb[(rt * 64 + lane) * 8];
        #pragma unroll
        for (int rt = 0; rt < 4; rt++)
            #pragma unroll
            for (int cc = 0; cc < 4; cc++)
                acc[rt][cc] = __builtin_amdgcn_mfma_f32_16x16x32_bf16(
                    af[rt], bcur[cc], acc[rt][cc], 0, 0, 0);

        // reload bcur with chunk kc+1 (global, same regs — R18-validated;
        // rides the lds-only barrier, vmcnt lands at next phase's MFMA)
        if (kc < 8) {
            #pragma unroll
            for (int cc = 0; cc < 4; cc++)
                bcur[cc] = bb[((kc + 1) * 16 + cc) * 64];
        }

        // generate av(kc+1) into BUF[Tg][(kc+1)&1]
        if (kc < 7) {
            floatx4 a0_ = u0, a1_ = u1, b0_ = v0, b1_ = v1;
            if (kc < 6) {                 // inputs for chunk kc+2
                u0 = *(const floatx4*)(hp_ptr + (kc + 2) * 32);
                u1 = *(const floatx4*)(hp_ptr + (kc + 2) * 32 + 4);
                v0 = *(const floatx4*)(ha_ptr + (kc + 2) * 32);
                v1 = *(const floatx4*)(ha_ptr + (kc + 2) * 32 + 4);
            }
            *(bf16x8*)(wbase + (((kc + 1) & 1) ? 2048 : 0)) =
                tanh_add8(a0_, a1_, b0_, b1_);
        } else if (kc == 7) {             // folded chunk 8: A = [bs(4),1,0..]
            bf16x8 av = {};
            if (k0 == 0) {
                #pragma unroll
                for (int j = 0; j < 4; j++) av[j] = (__bf16)bs4[j];
                av[4] = (__bf16)1.0f;     // k = 260 pairs with bmid row
            }
            *(bf16x8*)(wbase) = av;       // parity (8&1) == 0
        }

        if (kc < 8) barrier_lds_only();
    }

    // ---- epilogue: tanh(acc) . Wout (acc = K*mid), packed fp32 math,
    //      DPP row reduce, cross-wave LDS combine (4 waves per tile)
    float wo[4];
    #pragma unroll
    for (int cc = 0; cc < 4; cc++)
        wo[cc] = Wout[n * 256 + wq * 64 + cc * 16 + col16];

    const floatx2 onex2 = {1.0f, 1.0f};
    const floatx2 m2x2  = {-2.0f, -2.0f};
    #pragma unroll
    for (int rt = 0; rt < 4; rt++) {
        #pragma unroll
        for (int reg = 0; reg < 4; reg++) {
            floatx2 e01, e23;
            e01[0] = __builtin_amdgcn_exp2f(acc[rt][0][reg]);
            e01[1] = __builtin_amdgcn_exp2f(acc[rt][1][reg]);
            e23[0] = __builtin_amdgcn_exp2f(acc[rt][2][reg]);
            e23[1] = __builtin_amdgcn_exp2f(acc[rt][3][reg]);
            floatx2 d01 = pk_add2(e01, onex2);
            floatx2 d23 = pk_add2(e23, onex2);
            floatx2 rc01, rc23;
            rc01[0] = __builtin_amdgcn_rcpf(d01[0]);
            rc01[1] = __builtin_amdgcn_rcpf(d01[1]);
            rc23[0] = __builtin_amdgcn_rcpf(d23[0]);
            rc23[1] = __builtin_amdgcn_rcpf(d23[1]);
            floatx2 t01 = pk_fma2(rc01, m2x2, onex2);   // tanh = 1 - 2*rc
            floatx2 t23 = pk_fma2(rc23, m2x2, onex2);
            float rs = t01[0] * wo[0];
            rs = __builtin_fmaf(t01[1], wo[1], rs);
            rs = __builtin_fmaf(t23[0], wo[2], rs);
            rs = __builtin_fmaf(t23[1], wo[3], rs);
            rs = row16_reduce(rs);
            if (col16 == 0) red[w][rt * 16 + quad * 4 + reg] = rs;
        }
    }
    barrier_lds_only();

    if (tid < 128) {                      // 128 output rows (2 tiles x 64)
        const int T = tid >> 6, rid = tid & 63;
        float total = red[T * 4 + 0][rid] + red[T * 4 + 1][rid]
                    + red[T * 4 + 2][rid] + red[T * 4 + 3][rid];
        const int p = p0 + T * 8 + (rid >> 3), a = a0r + (rid & 7);
        out[((size_t)(b * LSEQ + p) * NCASE + n) * LSEQ + a] = total;
    }
}

// ---------------------------------------------------------------------------
extern "C" void kernel_launch(void* const* d_in, const int* in_sizes, int n_in,
                              void* d_out, int out_size, void* d_ws, size_t ws_size,
                              hipStream_t stream) {
    const float* seq  = (const float*)d_in[0];
    const float* bsc  = (const float*)d_in[1];
    const float* Wp   = (const float*)d_in[2];
    const float* bp   = (const float*)d_in[3];
    const float* Wa   = (const float*)d_in[4];
    const float* ba   = (const float*)d_in[5];
    const float* Wmid = (const float*)d_in[6];
    const float* bmid = (const float*)d_in[7];
    const float* Wout = (const float*)d_in[8];
    float* out = (float*)d_out;

    char* ws = (char*)d_ws;
    float*  lin   = (float*)(ws);                      // 1,966,080 B
    bf16x8* Bpack = (bf16x8*)(ws + 1966080);           //   589,824 B

    prep<<<2064, 256, 0, stream>>>(seq, Wp, Wa, bp, ba, Wmid, bmid, lin, Bpack);
    refine_main<<<dim3(288, NCASE, BATCH), 512, 0, stream>>>(
        lin, bsc, Wout, Bpack, out);
}

// Round 8
// 161.702 us; speedup vs baseline: 1.1110x; 1.1110x over previous
//
#include <hip/hip_runtime.h>

// Problem constants (RefinementLayer1): B=2, L=192, D=768, NC=4, H=256
#define LSEQ 192
#define DIM  768
#define NCASE 4
#define HID  256
#define BATCH 2

// tanh(x) = 1 - 2/(exp2(K*x)+1), K = 2*log2(e). K folded into Bpack so the
// refine epilogue's tanh input (acc = K*mid) needs no extra scale.
#define TANH_K 2.885390081777927f

typedef float  floatx4 __attribute__((ext_vector_type(4)));
typedef float  floatx2 __attribute__((ext_vector_type(2)));
typedef __bf16 bf16x8  __attribute__((ext_vector_type(8)));
typedef __bf16 bf16x4  __attribute__((ext_vector_type(4)));

__device__ __forceinline__ float tanh_pre(float x) {   // x already * TANH_K
    float e = __builtin_amdgcn_exp2f(x);
    return 1.0f - 2.0f * __builtin_amdgcn_rcpf(e + 1.0f);
}

// ---- packed fp32 pairs: NATIVE vector ops (backend selects v_pk_*_f32 with
// correct op_sel_hi; validated in R14-R18 passes).
__device__ __forceinline__ floatx2 pk_fma2(floatx2 a, floatx2 b, floatx2 c) {
    return __builtin_elementwise_fma(a, b, c);
}
__device__ __forceinline__ floatx2 pk_add2(floatx2 a, floatx2 b) { return a + b; }
__device__ __forceinline__ floatx2 pk_mul2(floatx2 a, floatx2 b) { return a * b; }

// tanh(u+v) = (tu+tv)/(1+tu*tv) from tu=tanh(u), tv=tanh(v).
// 4 elements packed: 2 pk_fma + 2 pk_add + 4 rcp + 2 pk_mul.
__device__ __forceinline__ bf16x4 tanh_add4(floatx4 u, floatx4 v) {
    const floatx2 one = {1.0f, 1.0f};
    bf16x4 r;
    #pragma unroll
    for (int i = 0; i < 2; i++) {
        floatx2 tu = {u[2 * i], u[2 * i + 1]};
        floatx2 tv = {v[2 * i], v[2 * i + 1]};
        floatx2 den = pk_fma2(tu, tv, one);
        floatx2 num = pk_add2(tu, tv);
        floatx2 rc;
        rc[0] = __builtin_amdgcn_rcpf(den[0]);
        rc[1] = __builtin_amdgcn_rcpf(den[1]);
        floatx2 res = pk_mul2(num, rc);
        r[2 * i]     = (__bf16)res[0];
        r[2 * i + 1] = (__bf16)res[1];
    }
    return r;
}

// Workgroup barrier draining ONLY lgkmcnt (LDS); global prefetches stay in
// flight. 0xC07F = vmcnt(63) expcnt(7) lgkmcnt(0).
__device__ __forceinline__ void barrier_lds_only() {
    __builtin_amdgcn_sched_barrier(0);
    __builtin_amdgcn_s_waitcnt(0xC07F);
    __builtin_amdgcn_s_barrier();
    __builtin_amdgcn_sched_barrier(0);
}

template <int CTRL>
__device__ __forceinline__ float dpp_add(float v) {
    int x = __builtin_amdgcn_update_dpp(0, __builtin_bit_cast(int, v),
                                        CTRL, 0xF, 0xF, true);
    return v + __builtin_bit_cast(float, x);
}
__device__ __forceinline__ float row16_reduce(float v) {
    v = dpp_add<0xB1>(v);    // quad_perm xor1
    v = dpp_add<0x4E>(v);    // quad_perm xor2
    v = dpp_add<0x141>(v);   // row_half_mirror
    v = dpp_add<0x140>(v);   // row_mirror
    return v;
}

// ---------------------------------------------------------------------------
// MFMA fragment layouts (m89/m91-verified, 16x16x32 bf16):
//   A: lane holds A[m = lane&15][k = (lane>>4)*8 + j]   (bf16x8)
//   B: lane holds B[k = (lane>>4)*8 + j][h = lane&15]   (bf16x8)
//   C/D: lane reg holds D[row = (lane>>4)*4 + reg][col = lane&15]
// ---------------------------------------------------------------------------

// ---------------------------------------------------------------------------
// Kernel 1 "prep" (unchanged — proven not the bottleneck).
// ---------------------------------------------------------------------------
__global__ __launch_bounds__(256) void prep(
    const float* __restrict__ seq, const float* __restrict__ Wp,
    const float* __restrict__ Wa,  const float* __restrict__ bp,
    const float* __restrict__ ba,  const float* __restrict__ Wmid,
    const float* __restrict__ bmid,
    float* __restrict__ lin, bf16x8* __restrict__ Bpack)
{
    const int blk = blockIdx.x;
    const int tid = threadIdx.x;

    if (blk >= 1920) {                     // ---- pack job
        int u = (blk - 1920) * 256 + tid;  // 0..36863 (one bf16x8 each)
        int lane = u & 63, f = u >> 6;
        int ct = f & 15, nk = f >> 4;      // nk = n*9 + kc
        int kc = nk % 9, n = nk / 9;
        int h = ct * 16 + (lane & 15);
        int kbase = kc * 32 + ((lane >> 4) & 3) * 8;
        bf16x8 v;
        #pragma unroll
        for (int j = 0; j < 8; j++) {
            int k = kbase + j;
            float x;
            if (k < 260)       x = Wmid[(size_t)(n * 260 + k) * 256 + h];
            else if (k == 260) x = bmid[n * 256 + h];
            else               x = 0.0f;
            v[j] = (__bf16)(TANH_K * x);
        }
        Bpack[u] = v;
        return;
    }

    // ---- lin unit: rt = blk/80, cg = blk%80; wave w = K-quarter
    const int w = tid >> 6, lane = tid & 63;
    const int rt = blk / 80, cg = blk % 80;
    const int quad  = lane >> 4;
    const int col16 = lane & 15;

    __shared__ float cmb[3][256];          // waves 1..3 partials, 3 KB

    const int arow = rt * 16 + col16;          // A: m = lane&15
    const int col  = cg * 16 + col16;          // output col 0..1279
    const int kofs = w * 192;
    const float* aptr = seq + (size_t)arow * DIM + kofs + quad * 8;
    const float* wbase = (cg < 16) ? (Wp + col) : (Wa + (col - 256));
    const int    wstr  = (cg < 16) ? HID : (NCASE * HID);

    floatx4 acc = {};
    floatx4 a0 = *(const floatx4*)(aptr);
    floatx4 a1 = *(const floatx4*)(aptr + 4);
    float bv[8];
    #pragma unroll
    for (int j = 0; j < 8; j++)
        bv[j] = wbase[(size_t)(kofs + quad * 8 + j) * wstr];

    #pragma unroll
    for (int kc = 0; kc < 6; kc++) {
        bf16x8 ah, al, bh, bl;
        #pragma unroll
        for (int j = 0; j < 4; j++) {
            __bf16 h0 = (__bf16)a0[j];
            ah[j] = h0; al[j] = (__bf16)(a0[j] - (float)h0);
            __bf16 h1 = (__bf16)a1[j];
            ah[4 + j] = h1; al[4 + j] = (__bf16)(a1[j] - (float)h1);
        }
        #pragma unroll
        for (int j = 0; j < 8; j++) {
            __bf16 h = (__bf16)bv[j];
            bh[j] = h; bl[j] = (__bf16)(bv[j] - (float)h);
        }
        if (kc < 5) {                      // prefetch next chunk
            a0 = *(const floatx4*)(aptr + (kc + 1) * 32);
            a1 = *(const floatx4*)(aptr + (kc + 1) * 32 + 4);
            #pragma unroll
            for (int j = 0; j < 8; j++)
                bv[j] = wbase[(size_t)(kofs + (kc + 1) * 32 + quad * 8 + j) * wstr];
        }
        acc = __builtin_amdgcn_mfma_f32_16x16x32_bf16(ah, bh, acc, 0, 0, 0);
        acc = __builtin_amdgcn_mfma_f32_16x16x32_bf16(al, bh, acc, 0, 0, 0);
        acc = __builtin_amdgcn_mfma_f32_16x16x32_bf16(ah, bl, acc, 0, 0, 0);
    }

    if (w > 0) *(floatx4*)&cmb[w - 1][lane * 4] = acc;
    __syncthreads();
    if (w == 0) {
        #pragma unroll
        for (int i = 0; i < 3; i++) {
            floatx4 p = *(const floatx4*)&cmb[i][lane * 4];
            acc += p;
        }
        const float bias = (cg < 16) ? bp[col] : ba[col - 256];
        #pragma unroll
        for (int reg = 0; reg < 4; reg++)
            lin[(size_t)(rt * 16 + quad * 4 + reg) * 1280 + col] =
                tanh_pre(TANH_K * (acc[reg] + bias));     // pre-activated
    }
}

// ---------------------------------------------------------------------------
// Kernel 2: fused main — R20: LDS-traffic halving at CONSTANT register cost.
// R19 retried the same theory but died on registers (acc[4][4]=64 VGPR ->
// spill, WRITE_SIZE 120MB). R20 redistributes instead of enlarging: same
// 64-row x 256-col block tile as R16, but wave w = (rg = w>>2, wq = w&3)
// reads only HALF the A-tile (af[2], 2x ds_read_b128) and covers
// 2 rt x 4 cc (rows rg*32..+31, cols wq*64..+63). Per-wave MFMA/phase
// unchanged (8); per-block LDS reads per phase HALVED (32 -> 16 b128);
// acc[2][4] = 32 VGPR = R16's bill. B regs double (bcur[4]+bnext[4]=32,
// R16-proven prefetch pattern) -> total ~100, under the (512,4) 128 cap
// (2.5x the R19 margin error); 38% occupancy shown ~free by R14/R15/R18.
// Everything else byte-identical to proven R16: half-slot tanh_add4 gen one
// chunk ahead, A0/A1 parity, lds-only barriers, packed fp32 epilogue.
// ---------------------------------------------------------------------------
__global__ __launch_bounds__(512, 4) void refine_main(
    const float* __restrict__ lin,        // [384][1280], PRE-TANH'd
    const float* __restrict__ base_score, // [B][L][NC][L]
    const float* __restrict__ Wout,       // [NC][256]
    const bf16x8* __restrict__ Bpack,     // packed Wmid frags (K-scaled)
    float* __restrict__ out)              // [B][L][NC][L]
{
    const int bx = blockIdx.x;            // 576 = 24*24
    const int n  = blockIdx.y;
    const int b  = blockIdx.z;
    const int ptile = bx / 24, atile = bx % 24;
    const int p0 = ptile * 8, a0r = atile * 8;

    const int tid   = threadIdx.x;
    const int w     = tid >> 6;           // wave 0..7
    const int lane  = tid & 63;
    const int quad  = lane >> 4;
    const int col16 = lane & 15;
    const int rg    = w >> 2;             // row-group: rows rg*32..rg*32+31
    const int wq    = w & 3;              // col-group: ct = wq*4 + cc

    __shared__ __align__(16) __bf16 A0[256 * 8];   // 4 KB frag buf (even kc)
    __shared__ __align__(16) __bf16 A1[256 * 8];   // 4 KB frag buf (odd kc)
    __shared__ float red[8][32];                   // 1 KB

    // A-gen half-slot: slot s = tid>>1 (l = s&63), half = tid&1. (R16 verbatim)
    const int s_g    = tid >> 1;
    const int h2     = tid & 1;
    const int l_g    = s_g & 63;
    const int m_gen  = ((s_g >> 6) << 4) + (l_g & 15);
    const int kq     = (l_g >> 4) * 8 + h2 * 4;
    const int quad_g = l_g >> 4;

    const int pg = p0 + (m_gen >> 3), ag = a0r + (m_gen & 7);
    const float* hp_ptr = lin + (size_t)(b * LSEQ + pg) * 1280 + kq;
    const float* ha_ptr = lin + (size_t)(b * LSEQ + ag) * 1280 + 256 + n * 256 + kq;

    // B frags for wave w: index ((n*9 + kc)*16 + wq*4 + cc)*64 + lane
    const bf16x8* bbase = Bpack + ((size_t)(n * 9) * 16 + wq * 4) * 64 + lane;

    // ---- prologue
    float bs4[4] = {};
    if (quad_g == 0 && h2 == 0) {
        #pragma unroll
        for (int j = 0; j < 4; j++)
            bs4[j] = base_score[((size_t)(b * LSEQ + pg) * NCASE + j) * LSEQ + ag];
    }

    bf16x8 bcur[4];
    #pragma unroll
    for (int cc = 0; cc < 4; cc++) bcur[cc] = bbase[cc * 64];

    floatx4 hp = *(const floatx4*)(hp_ptr);
    floatx4 ha = *(const floatx4*)(ha_ptr);
    {   // av(0) -> A0 (half-slot)
        *(bf16x4*)&A0[tid * 4] = tanh_add4(hp, ha);
    }
    hp = *(const floatx4*)(hp_ptr + 32);   // chunk 1 inputs
    ha = *(const floatx4*)(ha_ptr + 32);
    barrier_lds_only();

    floatx4 acc[2][4] = {};   // [rt2][cc] — 32 VGPR, same as R16

    #pragma unroll
    for (int kc = 0; kc < 9; kc++) {
        // B prefetch for chunk kc+1 (stays in flight across the barrier)
        bf16x8 bnext[4];
        if (kc < 8) {
            #pragma unroll
            for (int cc = 0; cc < 4; cc++)
                bnext[cc] = bbase[((kc + 1) * 16 + cc) * 64];
        }
        // generate av(kc+1) into the other buffer (overlaps MFMA below)
        if (kc < 7) {
            floatx4 u0 = hp, v0 = ha;
            if (kc < 6) {                 // prefetch inputs for chunk kc+2
                hp = *(const floatx4*)(hp_ptr + (kc + 2) * 32);
                ha = *(const floatx4*)(ha_ptr + (kc + 2) * 32);
            }
            __bf16* buf = ((kc + 1) & 1) ? A1 : A0;
            *(bf16x4*)&buf[tid * 4] = tanh_add4(u0, v0);
        } else if (kc == 7) {             // folded chunk: A = [bs(4), 1, 0...]
            bf16x4 av = {};
            if (quad_g == 0) {
                if (h2 == 0) {
                    #pragma unroll
                    for (int j = 0; j < 4; j++) av[j] = (__bf16)bs4[j];
                } else {
                    av[0] = (__bf16)1.0f;  // k = 4 pairs with bmid row
                }
            }
            *(bf16x4*)&A0[tid * 4] = av;   // (7+1)&1 == 0
        }

        // MFMA(kc) from buf[kc&1]: wave reads only its HALF of the A-tile
        const __bf16* rb = (kc & 1) ? A1 : A0;
        bf16x8 af[2];
        #pragma unroll
        for (int rt2 = 0; rt2 < 2; rt2++)
            af[rt2] = *(const bf16x8*)&rb[((rg * 2 + rt2) * 64 + lane) * 8];
        #pragma unroll
        for (int rt2 = 0; rt2 < 2; rt2++)
            #pragma unroll
            for (int cc = 0; cc < 4; cc++)
                acc[rt2][cc] = __builtin_amdgcn_mfma_f32_16x16x32_bf16(
                    af[rt2], bcur[cc], acc[rt2][cc], 0, 0, 0);
        #pragma unroll
        for (int cc = 0; cc < 4; cc++) bcur[cc] = bnext[cc];
        if (kc < 8) barrier_lds_only();
    }

    // ---- epilogue: tanh(acc) . Wout (acc = K*mid), packed fp32 math,
    //      DPP row reduce, cross-wave LDS combine (4 wq waves per row-group)
    float wo[4];
    #pragma unroll
    for (int cc = 0; cc < 4; cc++)
        wo[cc] = Wout[n * 256 + (wq * 4 + cc) * 16 + col16];

    const floatx2 onex2 = {1.0f, 1.0f};
    const floatx2 m2x2  = {-2.0f, -2.0f};
    #pragma unroll
    for (int rt2 = 0; rt2 < 2; rt2++) {
        #pragma unroll
        for (int reg = 0; reg < 4; reg++) {
            floatx2 e01, e23;
            e01[0] = __builtin_amdgcn_exp2f(acc[rt2][0][reg]);
            e01[1] = __builtin_amdgcn_exp2f(acc[rt2][1][reg]);
            e23[0] = __builtin_amdgcn_exp2f(acc[rt2][2][reg]);
            e23[1] = __builtin_amdgcn_exp2f(acc[rt2][3][reg]);
            floatx2 d01 = pk_add2(e01, onex2);
            floatx2 d23 = pk_add2(e23, onex2);
            floatx2 rc01, rc23;
            rc01[0] = __builtin_amdgcn_rcpf(d01[0]);
            rc01[1] = __builtin_amdgcn_rcpf(d01[1]);
            rc23[0] = __builtin_amdgcn_rcpf(d23[0]);
            rc23[1] = __builtin_amdgcn_rcpf(d23[1]);
            floatx2 t01 = pk_fma2(rc01, m2x2, onex2);   // tanh = 1 - 2*rc
            floatx2 t23 = pk_fma2(rc23, m2x2, onex2);
            float rs = t01[0] * wo[0];
            rs = __builtin_fmaf(t01[1], wo[1], rs);
            rs = __builtin_fmaf(t23[0], wo[2], rs);
            rs = __builtin_fmaf(t23[1], wo[3], rs);
            rs = row16_reduce(rs);
            if (col16 == 0) red[w][rt2 * 16 + quad * 4 + reg] = rs;
        }
    }
    barrier_lds_only();

    if (tid < 64) {                        // row m: rg = m>>5, r5 = m&31
        const int m  = tid;
        const int g  = m >> 5, r5 = m & 31;
        float total = red[g * 4 + 0][r5] + red[g * 4 + 1][r5]
                    + red[g * 4 + 2][r5] + red[g * 4 + 3][r5];
        const int p = p0 + (m >> 3), a = a0r + (m & 7);
        out[((size_t)(b * LSEQ + p) * NCASE + n) * LSEQ + a] = total;
    }
}

// ---------------------------------------------------------------------------
extern "C" void kernel_launch(void* const* d_in, const int* in_sizes, int n_in,
                              void* d_out, int out_size, void* d_ws, size_t ws_size,
                              hipStream_t stream) {
    const float* seq  = (const float*)d_in[0];
    const float* bsc  = (const float*)d_in[1];
    const float* Wp   = (const float*)d_in[2];
    const float* bp   = (const float*)d_in[3];
    const float* Wa   = (const float*)d_in[4];
    const float* ba   = (const float*)d_in[5];
    const float* Wmid = (const float*)d_in[6];
    const float* bmid = (const float*)d_in[7];
    const float* Wout = (const float*)d_in[8];
    float* out = (float*)d_out;

    char* ws = (char*)d_ws;
    float*  lin   = (float*)(ws);                      // 1,966,080 B
    bf16x8* Bpack = (bf16x8*)(ws + 1966080);           //   589,824 B

    prep<<<2064, 256, 0, stream>>>(seq, Wp, Wa, bp, ba, Wmid, bmid, lin, Bpack);
    refine_main<<<dim3(576, NCASE, BATCH), 512, 0, stream>>>(
        lin, bsc, Wout, Bpack, out);
}